// Round 2
// baseline (2101.306 us; speedup 1.0000x reference)
//
#include <hip/hip_runtime.h>
#include <math.h>

#define NTOK 32768
#define DDIM 768
#define HDIM 3072
#define NEXP 8
#define CAP  10240

typedef short short8 __attribute__((ext_vector_type(8)));
typedef float f32x4 __attribute__((ext_vector_type(4)));

__device__ __forceinline__ unsigned short f2bf(float f) {
  unsigned u = __float_as_uint(f);
  u += 0x7FFFu + ((u >> 16) & 1u);   // round-to-nearest-even (finite inputs)
  return (unsigned short)(u >> 16);
}

__device__ __forceinline__ void gload16(const void* g, void* l) {
  __builtin_amdgcn_global_load_lds(
      (const __attribute__((address_space(1))) void*)g,
      (__attribute__((address_space(3))) void*)l, 16, 0, 0);
}

// ---------------------------------------------------------------------------
// Router: logits = x @ w_gate, top-2, softmax(2), expert lists; also x -> bf16.
// ---------------------------------------------------------------------------
__global__ __launch_bounds__(256) void router_kernel(
    const float* __restrict__ x, const float* __restrict__ wg,
    unsigned short* __restrict__ xb, int* __restrict__ cnt,
    int* __restrict__ tokidx, float* __restrict__ tokw)
{
  __shared__ float wt[NEXP][DDIM];       // transposed gate, 24 KB
  int t = threadIdx.x;
  for (int idx = t; idx < NEXP * DDIM; idx += 256) {
    int d = idx >> 3, e = idx & 7;       // wg is [768][8] row-major
    wt[e][d] = wg[idx];
  }
  __syncthreads();
  int wave = t >> 6, lane = t & 63;
  int n0 = blockIdx.x * 32 + wave * 8;
  for (int i = 0; i < 8; ++i) {
    int n = n0 + i;
    const float* xr = x + (size_t)n * DDIM;
    unsigned short* xbr = xb + (size_t)n * DDIM;
    float acc[NEXP];
#pragma unroll
    for (int e = 0; e < NEXP; ++e) acc[e] = 0.f;
#pragma unroll
    for (int c = 0; c < 3; ++c) {
      int d = c * 256 + lane * 4;
      float4 xv = *(const float4*)(xr + d);
      ushort4 pk;
      pk.x = f2bf(xv.x); pk.y = f2bf(xv.y); pk.z = f2bf(xv.z); pk.w = f2bf(xv.w);
      *(ushort4*)(xbr + d) = pk;
#pragma unroll
      for (int e = 0; e < NEXP; ++e) {
        float4 wv = *(const float4*)(&wt[e][d]);
        acc[e] += xv.x * wv.x + xv.y * wv.y + xv.z * wv.z + xv.w * wv.w;
      }
    }
#pragma unroll
    for (int e = 0; e < NEXP; ++e) {
      float v = acc[e];
      for (int o = 32; o > 0; o >>= 1) v += __shfl_xor(v, o, 64);
      acc[e] = v;
    }
    if (lane == 0) {
      int e1 = 0; float l1 = acc[0];
#pragma unroll
      for (int e = 1; e < NEXP; ++e) if (acc[e] > l1) { l1 = acc[e]; e1 = e; }
      int e2 = -1; float l2 = -INFINITY;
#pragma unroll
      for (int e = 0; e < NEXP; ++e) if (e != e1 && acc[e] > l2) { l2 = acc[e]; e2 = e; }
      float p1 = 1.f / (1.f + expf(l2 - l1));   // stable 2-way softmax
      float p2 = 1.f - p1;
      int pos1 = atomicAdd(&cnt[e1], 1);
      if (pos1 < CAP) { tokidx[e1 * CAP + pos1] = n; tokw[e1 * CAP + pos1] = p1; }
      int pos2 = atomicAdd(&cnt[e2], 1);
      if (pos2 < CAP) { tokidx[e2 * CAP + pos2] = n; tokw[e2 * CAP + pos2] = p2; }
    }
  }
}

// ---------------------------------------------------------------------------
// Per-expert transpose + fp32->bf16: src [E][R][C] -> dst [E][C][R]
// ---------------------------------------------------------------------------
__global__ __launch_bounds__(256) void transpose_kernel(
    const float* __restrict__ src, unsigned short* __restrict__ dst, int R, int C)
{
  __shared__ float tile[64][65];
  int eb = blockIdx.z;
  const float* s = src + (size_t)eb * R * C;
  unsigned short* d = dst + (size_t)eb * R * C;
  int c0 = blockIdx.x * 64, r0 = blockIdx.y * 64;
  int tc = threadIdx.x & 63, tg = threadIdx.x >> 6;
#pragma unroll
  for (int rr = tg; rr < 64; rr += 4)
    tile[rr][tc] = s[(size_t)(r0 + rr) * C + c0 + tc];
  __syncthreads();
#pragma unroll
  for (int rr = tg; rr < 64; rr += 4)
    d[(size_t)(c0 + rr) * R + r0 + tc] = f2bf(tile[tc][rr]);
}

// ---------------------------------------------------------------------------
// Grouped GEMM, m97 structure. 128x128 tile, BK=64, 4 waves, 16x16x32 bf16.
// Chunked over M: this launch covers token rows [mbase, mbase+Mc) per expert;
// Hbuf rows are indexed (e*Mc + local_row).
// EPI=0: C = gelu(gather(xb) @ w1bt^T + b1) -> Hout (bf16)
// EPI=1: C = (Hbuf @ w2bt^T + b2) * tokw -> atomicAdd into Out (fp32)
// ---------------------------------------------------------------------------
template<int EPI, int KK, int NN>
__global__ __launch_bounds__(256, 2) void moe_gemm(
    const unsigned short* __restrict__ A,
    const unsigned short* __restrict__ Bt,
    const float* __restrict__ bias,
    const int* __restrict__ cnt,
    const int* __restrict__ tokidx,
    const float* __restrict__ tokw,
    unsigned short* __restrict__ Hout,
    float* __restrict__ Out,
    int mbase, int Mc)
{
  int e = blockIdx.z;
  int M = cnt[e]; if (M > CAP) M = CAP;
  int ly0 = blockIdx.y * 128;           // local row base within chunk
  int gm0 = mbase + ly0;                // global slot base
  if (gm0 >= M) return;
  int n0 = blockIdx.x * 128;
  int t = threadIdx.x, wave = t >> 6, lane = t & 63;
  int wr = wave >> 1, wc = wave & 1;
  int lane15 = lane & 15, quad = lane >> 4;

  __shared__ __align__(16) char smem[32768];
  char* ldsA = smem;
  char* ldsB = smem + 16384;

  // staging sources: 1024 16B chunks per tile, 4 issues per thread
  const unsigned short* ag[4];
  const unsigned short* bg[4];
#pragma unroll
  for (int i = 0; i < 4; ++i) {
    int li = i * 256 + t;
    int r = li >> 3;                    // tile row 0..127
    int c = (li & 7) ^ (r & 7);         // swizzled 16B chunk within row
    if (EPI == 0) {
      int gr = gm0 + r; if (gr >= M) gr = M - 1;   // clamp to a valid slot
      int ti = tokidx[e * CAP + gr];
      ag[i] = A + (size_t)ti * KK + c * 8;
    } else {
      ag[i] = A + ((size_t)e * Mc + ly0 + r) * KK + c * 8;
    }
    bg[i] = Bt + (size_t)e * NN * KK + (size_t)(n0 + r) * KK + c * 8;
  }

  // fragment LDS byte offsets (loop-invariant)
  int aoff[2][4], boff[2][4];
#pragma unroll
  for (int ks = 0; ks < 2; ++ks) {
#pragma unroll
    for (int f = 0; f < 4; ++f) {
      int ar = wr * 64 + f * 16 + lane15;
      aoff[ks][f] = ar * 128 + (((ks * 4 + quad) ^ (ar & 7)) * 16);
      int br = wc * 64 + f * 16 + lane15;
      boff[ks][f] = br * 128 + (((ks * 4 + quad) ^ (br & 7)) * 16);
    }
  }

  f32x4 acc[4][4];
#pragma unroll
  for (int mi = 0; mi < 4; ++mi)
#pragma unroll
    for (int ni = 0; ni < 4; ++ni)
#pragma unroll
      for (int r = 0; r < 4; ++r) acc[mi][ni][r] = 0.f;

  char* lwA = ldsA + wave * 1024;
  char* lwB = ldsB + wave * 1024;

  for (int kt = 0; kt < KK / 64; ++kt) {
    __syncthreads();                    // prev compute done before overwrite
#pragma unroll
    for (int i = 0; i < 4; ++i) {
      gload16(ag[i] + kt * 64, lwA + i * 4096);
      gload16(bg[i] + kt * 64, lwB + i * 4096);
    }
    __syncthreads();                    // drains vmcnt before barrier
#pragma unroll
    for (int ks = 0; ks < 2; ++ks) {
      short8 af[4], bf[4];
#pragma unroll
      for (int f = 0; f < 4; ++f) af[f] = *(const short8*)(ldsA + aoff[ks][f]);
#pragma unroll
      for (int f = 0; f < 4; ++f) bf[f] = *(const short8*)(ldsB + boff[ks][f]);
#pragma unroll
      for (int mi = 0; mi < 4; ++mi)
#pragma unroll
        for (int ni = 0; ni < 4; ++ni)
          acc[mi][ni] = __builtin_amdgcn_mfma_f32_16x16x32_bf16(
              af[mi], bf[ni], acc[mi][ni], 0, 0, 0);
    }
  }

  // epilogue: C/D layout col=lane&15, row=quad*4+reg  [m89-verified]
  if (EPI == 0) {
#pragma unroll
    for (int ni = 0; ni < 4; ++ni) {
      int col = n0 + wc * 64 + ni * 16 + lane15;
      float bcol = bias[e * NN + col];
#pragma unroll
      for (int mi = 0; mi < 4; ++mi) {
        int rowb = ly0 + wr * 64 + mi * 16 + quad * 4;   // local row
#pragma unroll
        for (int r = 0; r < 4; ++r) {
          float v = acc[mi][ni][r] + bcol;
          v = 0.5f * v * (1.f + erff(v * 0.70710678118654752f));  // exact GELU
          Hout[((size_t)e * Mc + rowb + r) * NN + col] = f2bf(v);
        }
      }
    }
  } else {
    float bc[4];
#pragma unroll
    for (int ni = 0; ni < 4; ++ni)
      bc[ni] = bias[e * NN + n0 + wc * 64 + ni * 16 + lane15];
#pragma unroll
    for (int mi = 0; mi < 4; ++mi) {
      int gmb = gm0 + wr * 64 + mi * 16 + quad * 4;      // global slot
#pragma unroll
      for (int r = 0; r < 4; ++r) {
        int gm = gmb + r;
        if (gm < M) {
          int tn = tokidx[e * CAP + gm];
          float w = tokw[e * CAP + gm];
          float* orow = Out + (size_t)tn * NN;
#pragma unroll
          for (int ni = 0; ni < 4; ++ni) {
            int col = n0 + wc * 64 + ni * 16 + lane15;
            atomicAdd(orow + col, (acc[mi][ni][r] + bc[ni]) * w);
          }
        }
      }
    }
  }
}

// ---------------------------------------------------------------------------
// LayerNorm in place over d_out rows of 768.
// ---------------------------------------------------------------------------
__global__ __launch_bounds__(256) void ln_kernel(
    float* __restrict__ out, const float* __restrict__ lnw, const float* __restrict__ lnb)
{
  __shared__ float red[8];
  int n = blockIdx.x;
  float* row = out + (size_t)n * DDIM;
  int t = threadIdx.x;
  float v0 = row[t], v1 = row[t + 256], v2 = row[t + 512];
  float s = v0 + v1 + v2;
  float ss = v0 * v0 + v1 * v1 + v2 * v2;
  for (int o = 32; o > 0; o >>= 1) { s += __shfl_xor(s, o, 64); ss += __shfl_xor(ss, o, 64); }
  int wave = t >> 6, lane = t & 63;
  if (lane == 0) { red[wave] = s; red[4 + wave] = ss; }
  __syncthreads();
  s = red[0] + red[1] + red[2] + red[3];
  ss = red[4] + red[5] + red[6] + red[7];
  float mu = s * (1.f / DDIM);
  float var = ss * (1.f / DDIM) - mu * mu;
  float rs = rsqrtf(var + 1e-5f);
  row[t] = (v0 - mu) * rs * lnw[t] + lnb[t];
  row[t + 256] = (v1 - mu) * rs * lnw[t + 256] + lnb[t + 256];
  row[t + 512] = (v2 - mu) * rs * lnw[t + 512] + lnb[t + 512];
}

// sentinel fill: signals "workspace too small" via a distinctive absmax
__global__ void sentinel_kernel(float* __restrict__ out, int n) {
  int i = blockIdx.x * 256 + threadIdx.x;
  if (i < n) out[i] = 12345.0f;
}

// ---------------------------------------------------------------------------
extern "C" void kernel_launch(void* const* d_in, const int* in_sizes, int n_in,
                              void* d_out, int out_size, void* d_ws, size_t ws_size,
                              hipStream_t stream)
{
  const float* x   = (const float*)d_in[0];
  const float* wg  = (const float*)d_in[1];
  const float* w1  = (const float*)d_in[2];
  const float* b1  = (const float*)d_in[3];
  const float* w2  = (const float*)d_in[4];
  const float* b2  = (const float*)d_in[5];
  const float* lnw = (const float*)d_in[6];
  const float* lnb = (const float*)d_in[7];
  float* out = (float*)d_out;

  char* ws = (char*)d_ws;
  size_t off = 0;
  auto take = [&](size_t bytes) {
    char* p = ws + off; off += (bytes + 255) & ~(size_t)255; return p;
  };
  unsigned short* xb   = (unsigned short*)take((size_t)NTOK * DDIM * 2);        // 50.3 MB
  unsigned short* w1bt = (unsigned short*)take((size_t)NEXP * DDIM * HDIM * 2); // 37.7 MB
  unsigned short* w2bt = (unsigned short*)take((size_t)NEXP * DDIM * HDIM * 2); // 37.7 MB
  int*   tokidx = (int*)take((size_t)NEXP * CAP * 4);
  float* tokw   = (float*)take((size_t)NEXP * CAP * 4);
  int*   cnt    = (int*)take(256);

  // Adaptive H-chunk: Mc token rows per expert, bounded by remaining workspace.
  size_t avail = (ws_size > off) ? (ws_size - off) : 0;
  long long cand = (long long)(avail / ((size_t)NEXP * HDIM * 2));  // rows/expert
  int Mc = (int)((cand / 128) * 128);
  if (Mc > CAP) Mc = CAP;
  if (Mc < 128) {   // cannot run at all — emit sentinel instead of crashing
    sentinel_kernel<<<(NTOK * DDIM + 255) / 256, 256, 0, stream>>>(out, NTOK * DDIM);
    return;
  }
  unsigned short* Hbuf = (unsigned short*)take((size_t)NEXP * Mc * HDIM * 2);

  hipMemsetAsync(cnt, 0, 256, stream);
  hipMemsetAsync(d_out, 0, (size_t)NTOK * DDIM * 4, stream);

  router_kernel<<<NTOK / 32, 256, 0, stream>>>(x, wg, xb, cnt, tokidx, tokw);
  transpose_kernel<<<dim3(HDIM / 64, DDIM / 64, NEXP), 256, 0, stream>>>(w1, w1bt, DDIM, HDIM);
  transpose_kernel<<<dim3(DDIM / 64, HDIM / 64, NEXP), 256, 0, stream>>>(w2, w2bt, HDIM, DDIM);

  for (int mbase = 0; mbase < CAP; mbase += Mc) {
    int rows = CAP - mbase; if (rows > Mc) rows = Mc;
    int mt = rows / 128;
    moe_gemm<0, DDIM, HDIM><<<dim3(HDIM / 128, mt, NEXP), 256, 0, stream>>>(
        xb, w1bt, b1, cnt, tokidx, tokw, Hbuf, nullptr, mbase, Mc);
    moe_gemm<1, HDIM, DDIM><<<dim3(DDIM / 128, mt, NEXP), 256, 0, stream>>>(
        Hbuf, w2bt, b2, cnt, tokidx, tokw, nullptr, out, mbase, Mc);
  }

  ln_kernel<<<NTOK, 256, 0, stream>>>(out, lnw, lnb);
}

// Round 3
// 1470.685 us; speedup vs baseline: 1.4288x; 1.4288x over previous
//
#include <hip/hip_runtime.h>
#include <math.h>

#define NTOK 32768
#define DDIM 768
#define HDIM 3072
#define NEXP 8
#define CAP  10240

typedef short short8 __attribute__((ext_vector_type(8)));
typedef float f32x4 __attribute__((ext_vector_type(4)));

__device__ __forceinline__ unsigned short f2bf(float f) {
  unsigned u = __float_as_uint(f);
  u += 0x7FFFu + ((u >> 16) & 1u);   // round-to-nearest-even (finite inputs)
  return (unsigned short)(u >> 16);
}
__device__ __forceinline__ float bf2f(unsigned short h) {
  return __uint_as_float((unsigned)h << 16);
}

__device__ __forceinline__ void gload16(const void* g, void* l) {
  __builtin_amdgcn_global_load_lds(
      (const __attribute__((address_space(1))) void*)g,
      (__attribute__((address_space(3))) void*)l, 16, 0, 0);
}

// ---------------------------------------------------------------------------
// Router phase 1: per-token top-2 + softmax -> pair/pw. Also x -> bf16.
// NO atomics.
// ---------------------------------------------------------------------------
__global__ __launch_bounds__(256) void router_assign(
    const float* __restrict__ x, const float* __restrict__ wg,
    unsigned short* __restrict__ xb,
    unsigned int* __restrict__ pair, float* __restrict__ pw)
{
  __shared__ float wt[NEXP][DDIM];       // transposed gate, 24 KB
  int t = threadIdx.x;
  for (int idx = t; idx < NEXP * DDIM; idx += 256) {
    int d = idx >> 3, e = idx & 7;       // wg is [768][8] row-major
    wt[e][d] = wg[idx];
  }
  __syncthreads();
  int wave = t >> 6, lane = t & 63;
  int n0 = blockIdx.x * 32 + wave * 8;
  for (int i = 0; i < 8; ++i) {
    int n = n0 + i;
    const float* xr = x + (size_t)n * DDIM;
    unsigned short* xbr = xb + (size_t)n * DDIM;
    float acc[NEXP];
#pragma unroll
    for (int e = 0; e < NEXP; ++e) acc[e] = 0.f;
#pragma unroll
    for (int c = 0; c < 3; ++c) {
      int d = c * 256 + lane * 4;
      float4 xv = *(const float4*)(xr + d);
      ushort4 pk;
      pk.x = f2bf(xv.x); pk.y = f2bf(xv.y); pk.z = f2bf(xv.z); pk.w = f2bf(xv.w);
      *(ushort4*)(xbr + d) = pk;
#pragma unroll
      for (int e = 0; e < NEXP; ++e) {
        float4 wv = *(const float4*)(&wt[e][d]);
        acc[e] += xv.x * wv.x + xv.y * wv.y + xv.z * wv.z + xv.w * wv.w;
      }
    }
#pragma unroll
    for (int e = 0; e < NEXP; ++e) {
      float v = acc[e];
      for (int o = 32; o > 0; o >>= 1) v += __shfl_xor(v, o, 64);
      acc[e] = v;
    }
    if (lane == 0) {
      int e1 = 0; float l1 = acc[0];
#pragma unroll
      for (int e = 1; e < NEXP; ++e) if (acc[e] > l1) { l1 = acc[e]; e1 = e; }
      int e2 = -1; float l2 = -INFINITY;
#pragma unroll
      for (int e = 0; e < NEXP; ++e) if (e != e1 && acc[e] > l2) { l2 = acc[e]; e2 = e; }
      float p1 = 1.f / (1.f + expf(l2 - l1));   // stable 2-way softmax
      pair[n] = (unsigned)e1 | ((unsigned)e2 << 8);
      pw[n] = p1;
    }
  }
}

// ---------------------------------------------------------------------------
// Router phase 2: one block per expert; compact token list in token order via
// ballot prefix-scan. NO global atomics. Also records per-token slot indices.
// ---------------------------------------------------------------------------
__global__ __launch_bounds__(256) void router_scatter(
    const unsigned int* __restrict__ pair, int* __restrict__ cnt,
    int* __restrict__ tokidx, int* __restrict__ slotof)
{
  int e = blockIdx.x;
  __shared__ int wsum[4];
  __shared__ int basev;
  int t = threadIdx.x, wave = t >> 6, lane = t & 63;
  if (t == 0) basev = 0;
  __syncthreads();
  for (int nb = 0; nb < NTOK; nb += 256) {
    int n = nb + t;
    unsigned p = pair[n];
    int e1 = p & 255, e2 = (p >> 8) & 255;
    bool m2 = (e2 == e);
    bool m = (e1 == e) | m2;
    unsigned long long bal = __ballot(m);
    int pre = __popcll(bal & ((1ull << lane) - 1ull));
    if (lane == 0) wsum[wave] = __popcll(bal);
    __syncthreads();
    int woff = 0;
    for (int wv = 0; wv < wave; ++wv) woff += wsum[wv];
    int tot = wsum[0] + wsum[1] + wsum[2] + wsum[3];
    int pos = basev + woff + pre;
    if (m) {
      if (pos < CAP) {
        tokidx[e * CAP + pos] = n;
        slotof[2 * n + (m2 ? 1 : 0)] = e * CAP + pos;
      } else {
        slotof[2 * n + (m2 ? 1 : 0)] = -1;   // dropped (never in practice)
      }
    }
    __syncthreads();
    if (t == 0) basev += tot;
  }
  __syncthreads();
  if (t == 0) cnt[e] = (basev < CAP) ? basev : CAP;
}

// ---------------------------------------------------------------------------
// Per-expert transpose + fp32->bf16: src [E][R][C] -> dst [E][C][R]
// ---------------------------------------------------------------------------
__global__ __launch_bounds__(256) void transpose_kernel(
    const float* __restrict__ src, unsigned short* __restrict__ dst, int R, int C)
{
  __shared__ float tile[64][65];
  int eb = blockIdx.z;
  const float* s = src + (size_t)eb * R * C;
  unsigned short* d = dst + (size_t)eb * R * C;
  int c0 = blockIdx.x * 64, r0 = blockIdx.y * 64;
  int tc = threadIdx.x & 63, tg = threadIdx.x >> 6;
#pragma unroll
  for (int rr = tg; rr < 64; rr += 4)
    tile[rr][tc] = s[(size_t)(r0 + rr) * C + c0 + tc];
  __syncthreads();
#pragma unroll
  for (int rr = tg; rr < 64; rr += 4)
    d[(size_t)(c0 + rr) * R + r0 + tc] = f2bf(tile[tc][rr]);
}

// ---------------------------------------------------------------------------
// Grouped GEMM, m97 structure. 128x128 tile, BK=64, 4 waves, 16x16x32 bf16.
// Chunked over M (rows [mbase, mbase+Mc) per expert).
// EPI=0: Obuf[e*Mc + row] = gelu(gather(xb) @ w1bt^T + b1)        (bf16)
// EPI=1: Obuf[e*CAP + gm] = Hbuf @ w2bt^T + b2  (bf16, un-weighted; no atomics)
// ---------------------------------------------------------------------------
template<int EPI, int KK, int NN>
__global__ __launch_bounds__(256, 2) void moe_gemm(
    const unsigned short* __restrict__ A,
    const unsigned short* __restrict__ Bt,
    const float* __restrict__ bias,
    const int* __restrict__ cnt,
    const int* __restrict__ tokidx,
    unsigned short* __restrict__ Obuf,
    int mbase, int Mc)
{
  int e = blockIdx.z;
  int M = cnt[e]; if (M > CAP) M = CAP;
  int ly0 = blockIdx.y * 128;           // local row base within chunk
  int gm0 = mbase + ly0;                // global slot base
  if (gm0 >= M) return;
  int n0 = blockIdx.x * 128;
  int t = threadIdx.x, wave = t >> 6, lane = t & 63;
  int wr = wave >> 1, wc = wave & 1;
  int lane15 = lane & 15, quad = lane >> 4;

  __shared__ __align__(16) char smem[32768];
  char* ldsA = smem;
  char* ldsB = smem + 16384;

  const unsigned short* ag[4];
  const unsigned short* bg[4];
#pragma unroll
  for (int i = 0; i < 4; ++i) {
    int li = i * 256 + t;
    int r = li >> 3;                    // tile row 0..127
    int c = (li & 7) ^ (r & 7);         // swizzled 16B chunk within row
    if (EPI == 0) {
      int gr = gm0 + r; if (gr >= M) gr = M - 1;   // clamp to a valid slot
      int ti = tokidx[e * CAP + gr];
      ag[i] = A + (size_t)ti * KK + c * 8;
    } else {
      ag[i] = A + ((size_t)e * Mc + ly0 + r) * KK + c * 8;
    }
    bg[i] = Bt + (size_t)e * NN * KK + (size_t)(n0 + r) * KK + c * 8;
  }

  int aoff[2][4], boff[2][4];
#pragma unroll
  for (int ks = 0; ks < 2; ++ks) {
#pragma unroll
    for (int f = 0; f < 4; ++f) {
      int ar = wr * 64 + f * 16 + lane15;
      aoff[ks][f] = ar * 128 + (((ks * 4 + quad) ^ (ar & 7)) * 16);
      int br = wc * 64 + f * 16 + lane15;
      boff[ks][f] = br * 128 + (((ks * 4 + quad) ^ (br & 7)) * 16);
    }
  }

  f32x4 acc[4][4];
#pragma unroll
  for (int mi = 0; mi < 4; ++mi)
#pragma unroll
    for (int ni = 0; ni < 4; ++ni)
#pragma unroll
      for (int r = 0; r < 4; ++r) acc[mi][ni][r] = 0.f;

  char* lwA = ldsA + wave * 1024;
  char* lwB = ldsB + wave * 1024;

  for (int kt = 0; kt < KK / 64; ++kt) {
    __syncthreads();
#pragma unroll
    for (int i = 0; i < 4; ++i) {
      gload16(ag[i] + kt * 64, lwA + i * 4096);
      gload16(bg[i] + kt * 64, lwB + i * 4096);
    }
    __syncthreads();
#pragma unroll
    for (int ks = 0; ks < 2; ++ks) {
      short8 af[4], bf[4];
#pragma unroll
      for (int f = 0; f < 4; ++f) af[f] = *(const short8*)(ldsA + aoff[ks][f]);
#pragma unroll
      for (int f = 0; f < 4; ++f) bf[f] = *(const short8*)(ldsB + boff[ks][f]);
#pragma unroll
      for (int mi = 0; mi < 4; ++mi)
#pragma unroll
        for (int ni = 0; ni < 4; ++ni)
          acc[mi][ni] = __builtin_amdgcn_mfma_f32_16x16x32_bf16(
              af[mi], bf[ni], acc[mi][ni], 0, 0, 0);
    }
  }

  // epilogue: C/D layout col=lane&15, row=quad*4+reg  [m89-verified]
  if (EPI == 0) {
#pragma unroll
    for (int ni = 0; ni < 4; ++ni) {
      int col = n0 + wc * 64 + ni * 16 + lane15;
      float bcol = bias[e * NN + col];
#pragma unroll
      for (int mi = 0; mi < 4; ++mi) {
        int rowb = ly0 + wr * 64 + mi * 16 + quad * 4;   // local row
#pragma unroll
        for (int r = 0; r < 4; ++r) {
          float v = acc[mi][ni][r] + bcol;
          v = 0.5f * v * (1.f + erff(v * 0.70710678118654752f));  // exact GELU
          Obuf[((size_t)e * Mc + rowb + r) * NN + col] = f2bf(v);
        }
      }
    }
  } else {
    float bc[4];
#pragma unroll
    for (int ni = 0; ni < 4; ++ni)
      bc[ni] = bias[e * NN + n0 + wc * 64 + ni * 16 + lane15];
#pragma unroll
    for (int mi = 0; mi < 4; ++mi) {
      int gmb = gm0 + wr * 64 + mi * 16 + quad * 4;      // global slot
#pragma unroll
      for (int r = 0; r < 4; ++r) {
        int gm = gmb + r;
        if (gm < M) {
          unsigned short* yrow = Obuf + ((size_t)e * CAP + gm) * NN;
#pragma unroll
          for (int ni = 0; ni < 4; ++ni) {
            int col = n0 + wc * 64 + ni * 16 + lane15;
            yrow[col] = f2bf(acc[mi][ni][r] + bc[ni]);
          }
        }
      }
    }
  }
}

// ---------------------------------------------------------------------------
// Fused combine (weighted sum of the token's two expert outputs) + LayerNorm.
// ---------------------------------------------------------------------------
__global__ __launch_bounds__(256) void combine_ln(
    const unsigned short* __restrict__ Y, const int* __restrict__ slotof,
    const float* __restrict__ pw,
    const float* __restrict__ lnw, const float* __restrict__ lnb,
    float* __restrict__ out)
{
  __shared__ float red[8];
  int n = blockIdx.x;
  int s0 = slotof[2 * n], s1 = slotof[2 * n + 1];
  float p0 = pw[n], p1 = 1.f - p0;
  const unsigned short* y0 = Y + (size_t)(s0 < 0 ? 0 : s0) * DDIM;
  const unsigned short* y1 = Y + (size_t)(s1 < 0 ? 0 : s1) * DDIM;
  if (s0 < 0) p0 = 0.f;
  if (s1 < 0) p1 = 0.f;
  int t = threadIdx.x;
  float v0 = p0 * bf2f(y0[t])       + p1 * bf2f(y1[t]);
  float v1 = p0 * bf2f(y0[t + 256]) + p1 * bf2f(y1[t + 256]);
  float v2 = p0 * bf2f(y0[t + 512]) + p1 * bf2f(y1[t + 512]);
  float s = v0 + v1 + v2;
  float ss = v0 * v0 + v1 * v1 + v2 * v2;
  for (int o = 32; o > 0; o >>= 1) { s += __shfl_xor(s, o, 64); ss += __shfl_xor(ss, o, 64); }
  int wave = t >> 6, lane = t & 63;
  if (lane == 0) { red[wave] = s; red[4 + wave] = ss; }
  __syncthreads();
  s = red[0] + red[1] + red[2] + red[3];
  ss = red[4] + red[5] + red[6] + red[7];
  float mu = s * (1.f / DDIM);
  float var = ss * (1.f / DDIM) - mu * mu;
  float rs = rsqrtf(var + 1e-5f);
  float* row = out + (size_t)n * DDIM;
  row[t]       = (v0 - mu) * rs * lnw[t]       + lnb[t];
  row[t + 256] = (v1 - mu) * rs * lnw[t + 256] + lnb[t + 256];
  row[t + 512] = (v2 - mu) * rs * lnw[t + 512] + lnb[t + 512];
}

// sentinel fill: signals "workspace too small" via a distinctive absmax
__global__ void sentinel_kernel(float* __restrict__ out, int n) {
  int i = blockIdx.x * 256 + threadIdx.x;
  if (i < n) out[i] = 12345.0f;
}

// ---------------------------------------------------------------------------
extern "C" void kernel_launch(void* const* d_in, const int* in_sizes, int n_in,
                              void* d_out, int out_size, void* d_ws, size_t ws_size,
                              hipStream_t stream)
{
  const float* x   = (const float*)d_in[0];
  const float* wg  = (const float*)d_in[1];
  const float* w1  = (const float*)d_in[2];
  const float* b1  = (const float*)d_in[3];
  const float* w2  = (const float*)d_in[4];
  const float* b2  = (const float*)d_in[5];
  const float* lnw = (const float*)d_in[6];
  const float* lnb = (const float*)d_in[7];
  float* out = (float*)d_out;

  char* ws = (char*)d_ws;
  size_t off = 0;
  auto take = [&](size_t bytes) {
    char* p = ws + off; off += (bytes + 255) & ~(size_t)255; return p;
  };
  unsigned short* xb   = (unsigned short*)take((size_t)NTOK * DDIM * 2);        // 50.3 MB
  unsigned short* w1bt = (unsigned short*)take((size_t)NEXP * DDIM * HDIM * 2); // 37.7 MB
  unsigned short* w2bt = (unsigned short*)take((size_t)NEXP * DDIM * HDIM * 2); // 37.7 MB
  int*   tokidx = (int*)take((size_t)NEXP * CAP * 4);
  unsigned int* pair = (unsigned int*)take((size_t)NTOK * 4);
  float* pw   = (float*)take((size_t)NTOK * 4);
  int*   slotof = (int*)take((size_t)NTOK * 2 * 4);
  int*   cnt  = (int*)take(256);
  unsigned short* Ybuf = (unsigned short*)take((size_t)NEXP * CAP * DDIM * 2);  // 125.8 MB

  // Adaptive H-chunk: Mc token rows per expert, bounded by remaining workspace.
  size_t avail = (ws_size > off) ? (ws_size - off) : 0;
  long long cand = (long long)(avail / ((size_t)NEXP * HDIM * 2));  // rows/expert
  int Mc = (int)((cand / 128) * 128);
  if (Mc > CAP) Mc = CAP;
  if (Mc < 128) {   // cannot run at all — emit sentinel instead of crashing
    sentinel_kernel<<<(NTOK * DDIM + 255) / 256, 256, 0, stream>>>(out, NTOK * DDIM);
    return;
  }
  unsigned short* Hbuf = (unsigned short*)take((size_t)NEXP * Mc * HDIM * 2);

  router_assign<<<NTOK / 32, 256, 0, stream>>>(x, wg, xb, pair, pw);
  transpose_kernel<<<dim3(HDIM / 64, DDIM / 64, NEXP), 256, 0, stream>>>(w1, w1bt, DDIM, HDIM);
  transpose_kernel<<<dim3(DDIM / 64, HDIM / 64, NEXP), 256, 0, stream>>>(w2, w2bt, HDIM, DDIM);
  router_scatter<<<NEXP, 256, 0, stream>>>(pair, cnt, tokidx, slotof);

  for (int mbase = 0; mbase < CAP; mbase += Mc) {
    int rows = CAP - mbase; if (rows > Mc) rows = Mc;
    int mt = rows / 128;
    moe_gemm<0, DDIM, HDIM><<<dim3(HDIM / 128, mt, NEXP), 256, 0, stream>>>(
        xb, w1bt, b1, cnt, tokidx, Hbuf, mbase, Mc);
    moe_gemm<1, HDIM, DDIM><<<dim3(DDIM / 128, mt, NEXP), 256, 0, stream>>>(
        Hbuf, w2bt, b2, cnt, tokidx, Ybuf, mbase, Mc);
  }

  combine_ln<<<NTOK, 256, 0, stream>>>(Ybuf, slotof, pw, lnw, lnb, out);
}